// Round 14
// baseline (76.061 us; speedup 1.0000x reference)
//
#include <hip/hip_runtime.h>
#include <hip/hip_cooperative_groups.h>
#include <math.h>

namespace cg = cooperative_groups;

#define NB 256
#define ND 2048
#define T_K 10.0f
#define LDSCAP 2048            // compacted-point capacity (float2 = 16 KB LDS)
#define SCAN2_BLOCKS 512       // fallback path only

// ===========================================================================
// FUSED cooperative kernel: 256 blocks (1/CU), 3 phases, 2 grid syncs.
//   P1: stats(row b) + probe chunk b (min d^2((0,1),q))        -> u0part[b]
//   P2: exact prune threshold; filter+compact+scan chunk b      -> partial
//       (chunk re-read is L2-hot: same block touched it in P1)
//   P3: block b min-reduces partial[.][b], T=exp(-k*sqrt(d2))   -> out[b]
// Pruning bound (exact, triangle ineq): q can be argmin for some sample only
// if d(c0,q) <= U0 + 2R', U0=min_q d(c0,q), R'=max_b d(c0,b). Threshold
// inflated 1e-4 to cover fp32 rounding; kept-point math identical to R11-13.
// ===========================================================================
__global__ __launch_bounds__(256) void fused_kernel(const float* __restrict__ feat,
                                                    const float* __restrict__ mus,
                                                    const float* __restrict__ sigmas,
                                                    float* __restrict__ stats,
                                                    float* __restrict__ u0part,
                                                    float* __restrict__ partial,
                                                    float* __restrict__ out,
                                                    int Q) {
    cg::grid_group grid = cg::this_grid();
    const int b    = blockIdx.x;
    const int tid  = threadIdx.x;
    const int lane = tid & 63, wid = tid >> 6;

    __shared__ float2 buf[LDSCAP];
    __shared__ float  red[4][NB];
    __shared__ float  ls[4], lq[4];
    __shared__ int    cnt;

    const int nquad = Q >> 2;
    const int chunk = (nquad + NB - 1) / NB;
    const int qs    = b * chunk;
    const int qe    = min(qs + chunk, nquad);
    const float4* mu4 = (const float4*)mus;
    const float4* sg4 = (const float4*)sigmas;

    // ---------------- Phase 1a: stats for feature row b ----------------
    {
        const float4* row = (const float4*)(feat + (size_t)b * ND);
        float sum = 0.f, sumsq = 0.f;
#pragma unroll
        for (int i = 0; i < 2; ++i) {
            float4 v = row[tid + i * 256];
            sum   += v.x + v.y + v.z + v.w;
            sumsq += v.x * v.x + v.y * v.y + v.z * v.z + v.w * v.w;
        }
#pragma unroll
        for (int off = 32; off > 0; off >>= 1) {
            sum   += __shfl_down(sum, off, 64);
            sumsq += __shfl_down(sumsq, off, 64);
        }
        if (lane == 0) { ls[wid] = sum; lq[wid] = sumsq; }
        __syncthreads();
        if (tid == 0) {
            float S  = ls[0] + ls[1] + ls[2] + ls[3];
            float Q2 = lq[0] + lq[1] + lq[2] + lq[3];
            float mean = S / (float)ND;
            float var  = fmaxf((Q2 - S * mean) / (float)(ND - 1), 0.f);
            stats[b]      = mean;
            stats[NB + b] = sqrtf(var);
        }
    }

    // ---------------- Phase 1b: probe chunk b (warms this XCD's L2) ----------------
    {
        float best = INFINITY;
        for (int i = qs + tid; i < qe; i += 256) {
            float4 mu = mu4[i], sg = sg4[i];
            float s0 = sg.x - 1.f, s1 = sg.y - 1.f, s2e = sg.z - 1.f, s3 = sg.w - 1.f;
            best = fminf(best, fmaf(mu.x, mu.x, s0 * s0));
            best = fminf(best, fmaf(mu.y, mu.y, s1 * s1));
            best = fminf(best, fmaf(mu.z, mu.z, s2e * s2e));
            best = fminf(best, fmaf(mu.w, mu.w, s3 * s3));
        }
        if (b == 0) {                       // element tail (Q % 4)
            int q = nquad * 4 + tid;
            if (q < Q) {
                float dm = mus[q], ds = sigmas[q] - 1.f;
                best = fminf(best, fmaf(dm, dm, ds * ds));
            }
        }
#pragma unroll
        for (int off = 32; off > 0; off >>= 1)
            best = fminf(best, __shfl_down(best, off, 64));
        __syncthreads();                    // ls[] reuse
        if (lane == 0) ls[wid] = best;
        __syncthreads();
        if (tid == 0)
            u0part[b] = fminf(fminf(ls[0], ls[1]), fminf(ls[2], ls[3]));
    }

    grid.sync();

    // ---------------- Phase 2: threshold + filter + compact scan ----------------
    const float mb = stats[tid], sb = stats[NB + tid];
    __syncthreads();   // ls/lq reuse
    {
        float u = u0part[tid];
        float dsb = sb - 1.f;
        float r2 = fmaf(mb, mb, dsb * dsb);
#pragma unroll
        for (int off = 32; off > 0; off >>= 1) {
            u  = fminf(u,  __shfl_down(u,  off, 64));
            r2 = fmaxf(r2, __shfl_down(r2, off, 64));
        }
        if (lane == 0) { ls[wid] = u; lq[wid] = r2; }
        if (tid == 0) cnt = 0;
    }
    __syncthreads();
    const float U0   = fminf(fminf(ls[0], ls[1]), fminf(ls[2], ls[3]));
    const float R2   = fmaxf(fmaxf(lq[0], lq[1]), fmaxf(lq[2], lq[3]));
    const float thr  = sqrtf(U0) + 2.f * sqrtf(R2);
    const float thr2 = thr * thr * 1.0001f + 1e-12f;

    float m2[4], s2[4];
#pragma unroll
    for (int k = 0; k < 4; ++k) {
        m2[k] = -2.f * stats[lane + 64 * k];
        s2[k] = -2.f * stats[NB + lane + 64 * k];
    }
    float acc[4];
#pragma unroll
    for (int k = 0; k < 4; ++k) acc[k] = INFINITY;

    for (int base = qs; base < qe; base += 256) {
        __syncthreads();                              // appends settled, cnt uniform
        if (cnt > LDSCAP - 1024) {                    // room for worst-case 1024 appends
            const int n = cnt;
            for (int j = wid; j < n; j += 4) {
                float2 p = buf[j];
                float r = fmaf(p.x, p.x, p.y * p.y);
#pragma unroll
                for (int k = 0; k < 4; ++k)
                    acc[k] = fminf(acc[k], fmaf(m2[k], p.x, fmaf(s2[k], p.y, r)));
            }
            __syncthreads();
            if (tid == 0) cnt = 0;
            __syncthreads();
        }
        const int i = base + tid;
        if (i < qe) {
            float4 mu = mu4[i], sg = sg4[i];
#define TESTK(MX, SX)                                                        \
            {                                                                \
                float dm = (MX), dss = (SX) - 1.f;                           \
                float dd = fmaf(dm, dm, dss * dss);                          \
                if (dd <= thr2) {                                            \
                    int p = atomicAdd(&cnt, 1);                              \
                    buf[p] = make_float2((MX), (SX));                        \
                }                                                            \
            }
            TESTK(mu.x, sg.x)
            TESTK(mu.y, sg.y)
            TESTK(mu.z, sg.z)
            TESTK(mu.w, sg.w)
        }
    }
    if (b == 0) {                                     // element tail (empty for Q=880880)
        int q = nquad * 4 + tid;
        if (q < Q) { TESTK(mus[q], sigmas[q]) }
    }
#undef TESTK

    __syncthreads();
    {
        const int n = cnt;
        for (int j = wid; j < n; j += 4) {
            float2 p = buf[j];
            float r = fmaf(p.x, p.x, p.y * p.y);
#pragma unroll
            for (int k = 0; k < 4; ++k)
                acc[k] = fminf(acc[k], fmaf(m2[k], p.x, fmaf(s2[k], p.y, r)));
        }
    }

    __syncthreads();
#pragma unroll
    for (int k = 0; k < 4; ++k) red[wid][lane + 64 * k] = acc[k];
    __syncthreads();
    {
        float v = fminf(fminf(red[0][tid], red[1][tid]), fminf(red[2][tid], red[3][tid]));
        v = v + fmaf(mb, mb, sb * sb);                // un-shift by c_b
        partial[(size_t)b * NB + tid] = fmaxf(v, 0.f);
    }

    grid.sync();

    // ---------------- Phase 3: block b reduces sample b, final transform ----------------
    {
        float v = partial[(size_t)tid * NB + b];      // L2-hot (512 KB total)
#pragma unroll
        for (int off = 32; off > 0; off >>= 1)
            v = fminf(v, __shfl_down(v, off, 64));
        __syncthreads();                              // ls reuse
        if (lane == 0) ls[wid] = v;
        __syncthreads();
        if (tid == 0) {
            float m = fminf(fminf(ls[0], ls[1]), fminf(ls[2], ls[3]));
            out[b] = expf(-T_K * sqrtf(m));
        }
    }
}

// ===========================================================================
// Fallback path (R13, proven 17.4 us): 3 separate kernels.
// ===========================================================================
__global__ __launch_bounds__(256) void stats_probe_kernel(const float* __restrict__ feat,
                                                          const float* __restrict__ mus,
                                                          const float* __restrict__ sigmas,
                                                          float* __restrict__ stats,
                                                          float* __restrict__ u0part,
                                                          int Q) {
    const int b    = blockIdx.x;
    const int tid  = threadIdx.x;
    const int lane = tid & 63, wid = tid >> 6;
    __shared__ float ls[4], lq[4];

    const float4* row = (const float4*)(feat + (size_t)b * ND);
    float sum = 0.f, sumsq = 0.f;
#pragma unroll
    for (int i = 0; i < 2; ++i) {
        float4 v = row[tid + i * 256];
        sum   += v.x + v.y + v.z + v.w;
        sumsq += v.x * v.x + v.y * v.y + v.z * v.z + v.w * v.w;
    }
#pragma unroll
    for (int off = 32; off > 0; off >>= 1) {
        sum   += __shfl_down(sum, off, 64);
        sumsq += __shfl_down(sumsq, off, 64);
    }
    if (lane == 0) { ls[wid] = sum; lq[wid] = sumsq; }
    __syncthreads();
    if (tid == 0) {
        float S  = ls[0] + ls[1] + ls[2] + ls[3];
        float Q2 = lq[0] + lq[1] + lq[2] + lq[3];
        float mean = S / (float)ND;
        float var  = fmaxf((Q2 - S * mean) / (float)(ND - 1), 0.f);
        stats[b]      = mean;
        stats[NB + b] = sqrtf(var);
    }

    const int nquad = Q >> 2;
    const int chunk = (nquad + NB - 1) / NB;
    const int qs    = b * chunk;
    const int qe    = min(qs + chunk, nquad);
    const float4* mu4 = (const float4*)mus;
    const float4* sg4 = (const float4*)sigmas;

    float best = INFINITY;
    for (int i = qs + tid; i < qe; i += 256) {
        float4 mu = mu4[i], sg = sg4[i];
        float s0 = sg.x - 1.f, s1 = sg.y - 1.f, s2e = sg.z - 1.f, s3 = sg.w - 1.f;
        best = fminf(best, fmaf(mu.x, mu.x, s0 * s0));
        best = fminf(best, fmaf(mu.y, mu.y, s1 * s1));
        best = fminf(best, fmaf(mu.z, mu.z, s2e * s2e));
        best = fminf(best, fmaf(mu.w, mu.w, s3 * s3));
    }
    if (b == 0) {
        int q = nquad * 4 + tid;
        if (q < Q) {
            float dm = mus[q], ds = sigmas[q] - 1.f;
            best = fminf(best, fmaf(dm, dm, ds * ds));
        }
    }
#pragma unroll
    for (int off = 32; off > 0; off >>= 1)
        best = fminf(best, __shfl_down(best, off, 64));
    __syncthreads();
    if (lane == 0) ls[wid] = best;
    __syncthreads();
    if (tid == 0)
        u0part[b] = fminf(fminf(ls[0], ls[1]), fminf(ls[2], ls[3]));
}

__global__ __launch_bounds__(256) void scan_filtered_kernel(const float* __restrict__ mus,
                                                            const float* __restrict__ sigmas,
                                                            const float* __restrict__ stats,
                                                            const float* __restrict__ u0part,
                                                            float* __restrict__ partial,
                                                            int Q) {
    const int tid  = threadIdx.x;
    const int lane = tid & 63, wid = tid >> 6;

    __shared__ float2 buf[LDSCAP];
    __shared__ float  red[4][NB];
    __shared__ float  ls[4], lq[4];
    __shared__ int    cnt;

    float u = u0part[tid];
    float mb = stats[tid], sb = stats[NB + tid];
    float dsb = sb - 1.f;
    float r2 = fmaf(mb, mb, dsb * dsb);
#pragma unroll
    for (int off = 32; off > 0; off >>= 1) {
        u  = fminf(u,  __shfl_down(u,  off, 64));
        r2 = fmaxf(r2, __shfl_down(r2, off, 64));
    }
    if (lane == 0) { ls[wid] = u; lq[wid] = r2; }
    if (tid == 0) cnt = 0;
    __syncthreads();
    const float U0   = fminf(fminf(ls[0], ls[1]), fminf(ls[2], ls[3]));
    const float R2   = fmaxf(fmaxf(lq[0], lq[1]), fmaxf(lq[2], lq[3]));
    const float thr  = sqrtf(U0) + 2.f * sqrtf(R2);
    const float thr2 = thr * thr * 1.0001f + 1e-12f;

    float m2[4], s2[4];
#pragma unroll
    for (int k = 0; k < 4; ++k) {
        m2[k] = -2.f * stats[lane + 64 * k];
        s2[k] = -2.f * stats[NB + lane + 64 * k];
    }
    float acc[4];
#pragma unroll
    for (int k = 0; k < 4; ++k) acc[k] = INFINITY;

    const int nquad = Q >> 2;
    const float4* mu4 = (const float4*)mus;
    const float4* sg4 = (const float4*)sigmas;

    for (int cb = blockIdx.x * 256; cb < nquad; cb += SCAN2_BLOCKS * 256) {
        __syncthreads();
        if (cnt > LDSCAP - 1024) {
            const int n = cnt;
            for (int j = wid; j < n; j += 4) {
                float2 p = buf[j];
                float r = fmaf(p.x, p.x, p.y * p.y);
#pragma unroll
                for (int k = 0; k < 4; ++k)
                    acc[k] = fminf(acc[k], fmaf(m2[k], p.x, fmaf(s2[k], p.y, r)));
            }
            __syncthreads();
            if (tid == 0) cnt = 0;
            __syncthreads();
        }
        const int i = cb + tid;
        if (i < nquad) {
            float4 mu = mu4[i], sg = sg4[i];
#define TESTK(MX, SX)                                                        \
            {                                                                \
                float dm = (MX), dss = (SX) - 1.f;                           \
                float dd = fmaf(dm, dm, dss * dss);                          \
                if (dd <= thr2) {                                            \
                    int p = atomicAdd(&cnt, 1);                              \
                    buf[p] = make_float2((MX), (SX));                        \
                }                                                            \
            }
            TESTK(mu.x, sg.x)
            TESTK(mu.y, sg.y)
            TESTK(mu.z, sg.z)
            TESTK(mu.w, sg.w)
        }
    }
    if (blockIdx.x == 0) {
        int q = nquad * 4 + tid;
        if (q < Q) { TESTK(mus[q], sigmas[q]) }
    }
#undef TESTK

    __syncthreads();
    {
        const int n = cnt;
        for (int j = wid; j < n; j += 4) {
            float2 p = buf[j];
            float r = fmaf(p.x, p.x, p.y * p.y);
#pragma unroll
            for (int k = 0; k < 4; ++k)
                acc[k] = fminf(acc[k], fmaf(m2[k], p.x, fmaf(s2[k], p.y, r)));
        }
    }

    __syncthreads();
#pragma unroll
    for (int k = 0; k < 4; ++k) red[wid][lane + 64 * k] = acc[k];
    __syncthreads();
    float v = fminf(fminf(red[0][tid], red[1][tid]), fminf(red[2][tid], red[3][tid]));
    v = v + fmaf(mb, mb, sb * sb);
    partial[(size_t)blockIdx.x * NB + tid] = fmaxf(v, 0.f);
}

__global__ __launch_bounds__(256) void reduce_kernel(const float* __restrict__ partial,
                                                     float* __restrict__ out,
                                                     int nblocks) {
    const int b   = blockIdx.x;
    const int tid = threadIdx.x;
    float v = INFINITY;
    for (int i = tid; i < nblocks; i += 256)
        v = fminf(v, partial[(size_t)i * NB + b]);
#pragma unroll
    for (int off = 32; off > 0; off >>= 1)
        v = fminf(v, __shfl_down(v, off, 64));
    __shared__ float w[4];
    const int lane = tid & 63, wid = tid >> 6;
    if (lane == 0) w[wid] = v;
    __syncthreads();
    if (tid == 0) {
        float m = fminf(fminf(w[0], w[1]), fminf(w[2], w[3]));
        out[b] = expf(-T_K * sqrtf(m));
    }
}

extern "C" void kernel_launch(void* const* d_in, const int* in_sizes, int n_in,
                              void* d_out, int out_size, void* d_ws, size_t ws_size,
                              hipStream_t stream) {
    const float* features = (const float*)d_in[0];
    // d_in[1]=labels, d_in[2]=pred, d_in[3]=confidence -- unused by reference
    const float* queue_mus    = (const float*)d_in[4];
    const float* queue_sigmas = (const float*)d_in[5];
    int Q = in_sizes[4];

    float* stats   = (float*)d_ws;                 // 2*NB floats
    float* u0part  = stats + 2 * NB;               // NB floats
    float* partial = u0part + NB;                  // max(SCAN2_BLOCKS,NB)*NB floats

    float* out = (float*)d_out;
    void* args[] = { (void*)&features, (void*)&queue_mus, (void*)&queue_sigmas,
                     (void*)&stats, (void*)&u0part, (void*)&partial,
                     (void*)&out, (void*)&Q };
    hipError_t err = hipLaunchCooperativeKernel((void*)fused_kernel,
                                                dim3(NB), dim3(256),
                                                args, 0, stream);
    if (err != hipSuccess) {
        // fallback: proven 3-kernel path (R13)
        stats_probe_kernel<<<NB, 256, 0, stream>>>(features, queue_mus, queue_sigmas,
                                                   stats, u0part, Q);
        scan_filtered_kernel<<<SCAN2_BLOCKS, 256, 0, stream>>>(queue_mus, queue_sigmas,
                                                               stats, u0part, partial, Q);
        reduce_kernel<<<NB, 256, 0, stream>>>(partial, out, SCAN2_BLOCKS);
    }
}

// Round 15
// 19.095 us; speedup vs baseline: 3.9834x; 3.9834x over previous
//
#include <hip/hip_runtime.h>
#include <math.h>

#define NB 256
#define ND 2048
#define T_K 10.0f
#define LDSCAP 2048            // compacted-point capacity (float2 = 16 KB LDS)

// ---------------------------------------------------------------------------
// K1: per-row mean & std (ddof=1). One block per row; 2 float4 per thread.
// (R14 post-mortem: cooperative grid.sync cost ~25us each on 8 XCDs -> back
//  to 3 plain kernels. Queue probe moved into K2 as a per-chunk local bound,
//  deleting K1's 7MB queue stream entirely.)
// ---------------------------------------------------------------------------
__global__ __launch_bounds__(256) void stats_kernel(const float* __restrict__ feat,
                                                    float* __restrict__ stats) {
    const int b   = blockIdx.x;
    const int tid = threadIdx.x;
    const int lane = tid & 63, wid = tid >> 6;
    __shared__ float ls[4], lq[4];

    const float4* row = (const float4*)(feat + (size_t)b * ND);
    float sum = 0.f, sumsq = 0.f;
#pragma unroll
    for (int i = 0; i < 2; ++i) {
        float4 v = row[tid + i * 256];
        sum   += v.x + v.y + v.z + v.w;
        sumsq += v.x * v.x + v.y * v.y + v.z * v.z + v.w * v.w;
    }
#pragma unroll
    for (int off = 32; off > 0; off >>= 1) {
        sum   += __shfl_down(sum, off, 64);
        sumsq += __shfl_down(sumsq, off, 64);
    }
    if (lane == 0) { ls[wid] = sum; lq[wid] = sumsq; }
    __syncthreads();
    if (tid == 0) {
        float S  = ls[0] + ls[1] + ls[2] + ls[3];
        float Q2 = lq[0] + lq[1] + lq[2] + lq[3];
        float mean = S / (float)ND;
        float var  = fmaxf((Q2 - S * mean) / (float)(ND - 1), 0.f);
        stats[b]      = mean;
        stats[NB + b] = sqrtf(var);
    }
}

// ---------------------------------------------------------------------------
// K2: per-chunk probe + exact local pruning + compact scan. 256 blocks.
// Chunk-local bound (exact, per-chunk): for q in chunk C, if
//   d(c0,q) > U0_loc(C) + 2R'   (U0_loc = min over C of d(c0,q),
//                                R' = max_b d(c0, (mean_b,std_b)), c0=(0,1))
// then d(b,q) >= d(c0,q)-R' > U0_loc+R' >= d(b, q0_loc) for the local probe
// winner q0_loc (which always passes the filter) -> dropping q cannot change
// C's partial min. Global min = min over chunks. Threshold inflated 1e-4 for
// fp32 rounding. Pass A (probe) warms this XCD's L2 (55KB/block, 1.8MB/XCD);
// pass B (filter) re-reads L2-hot, compacts ~2% into LDS, broadcast-scans.
// ---------------------------------------------------------------------------
__global__ __launch_bounds__(256) void scan_pruned_kernel(const float* __restrict__ mus,
                                                          const float* __restrict__ sigmas,
                                                          const float* __restrict__ stats,
                                                          float* __restrict__ partial,  // [NB*NB]
                                                          int Q) {
    const int b    = blockIdx.x;
    const int tid  = threadIdx.x;
    const int lane = tid & 63, wid = tid >> 6;

    __shared__ float2 buf[LDSCAP];
    __shared__ float  red[4][NB];
    __shared__ float  ls[4], lq[4];
    __shared__ int    cnt;

    const int nquad = Q >> 2;
    const int chunk = (nquad + NB - 1) / NB;
    const int qs    = b * chunk;
    const int qe    = min(qs + chunk, nquad);
    const float4* mu4 = (const float4*)mus;
    const float4* sg4 = (const float4*)sigmas;

    // ---- pass A: lane-parallel probe of this chunk: U0_loc ----
    float best = INFINITY;
    for (int i = qs + tid; i < qe; i += 256) {
        float4 mu = mu4[i], sg = sg4[i];
        float s0 = sg.x - 1.f, s1 = sg.y - 1.f, s2e = sg.z - 1.f, s3 = sg.w - 1.f;
        best = fminf(best, fmaf(mu.x, mu.x, s0 * s0));
        best = fminf(best, fmaf(mu.y, mu.y, s1 * s1));
        best = fminf(best, fmaf(mu.z, mu.z, s2e * s2e));
        best = fminf(best, fmaf(mu.w, mu.w, s3 * s3));
    }
    if (b == 0) {                       // element tail (Q % 4) joins block 0's chunk
        int q = nquad * 4 + tid;
        if (q < Q) {
            float dm = mus[q], ds = sigmas[q] - 1.f;
            best = fminf(best, fmaf(dm, dm, ds * ds));
        }
    }

    // ---- R'^2 from stats (one sample per thread) + block reduces ----
    const float mb = stats[tid], sb = stats[NB + tid];
    {
        float dsb = sb - 1.f;
        float r2 = fmaf(mb, mb, dsb * dsb);
#pragma unroll
        for (int off = 32; off > 0; off >>= 1) {
            best = fminf(best, __shfl_down(best, off, 64));
            r2   = fmaxf(r2,   __shfl_down(r2,   off, 64));
        }
        if (lane == 0) { ls[wid] = best; lq[wid] = r2; }
        if (tid == 0) cnt = 0;
    }
    __syncthreads();
    const float U0   = fminf(fminf(ls[0], ls[1]), fminf(ls[2], ls[3]));
    const float R2   = fmaxf(fmaxf(lq[0], lq[1]), fmaxf(lq[2], lq[3]));
    const float thr  = sqrtf(U0) + 2.f * sqrtf(R2);
    const float thr2 = thr * thr * 1.0001f + 1e-12f;

    // per-lane sample constants (samples b = lane + 64k)
    float m2[4], s2[4];
#pragma unroll
    for (int k = 0; k < 4; ++k) {
        m2[k] = -2.f * stats[lane + 64 * k];
        s2[k] = -2.f * stats[NB + lane + 64 * k];
    }
    float acc[4];
#pragma unroll
    for (int k = 0; k < 4; ++k) acc[k] = INFINITY;

    // ---- pass B: filter (L2-hot re-read) + compact + flush-scan ----
    for (int base = qs; base < qe; base += 256) {
        __syncthreads();                              // appends settled, cnt uniform
        if (cnt > LDSCAP - 1024) {                    // room for worst-case 1024 appends
            const int n = cnt;
            for (int j = wid; j < n; j += 4) {
                float2 p = buf[j];
                float r = fmaf(p.x, p.x, p.y * p.y);
#pragma unroll
                for (int k = 0; k < 4; ++k)
                    acc[k] = fminf(acc[k], fmaf(m2[k], p.x, fmaf(s2[k], p.y, r)));
            }
            __syncthreads();
            if (tid == 0) cnt = 0;
            __syncthreads();
        }
        const int i = base + tid;
        if (i < qe) {
            float4 mu = mu4[i], sg = sg4[i];
#define TESTK(MX, SX)                                                        \
            {                                                                \
                float dm = (MX), dss = (SX) - 1.f;                           \
                float dd = fmaf(dm, dm, dss * dss);                          \
                if (dd <= thr2) {                                            \
                    int p = atomicAdd(&cnt, 1);                              \
                    buf[p] = make_float2((MX), (SX));                        \
                }                                                            \
            }
            TESTK(mu.x, sg.x)
            TESTK(mu.y, sg.y)
            TESTK(mu.z, sg.z)
            TESTK(mu.w, sg.w)
        }
    }
    if (b == 0) {                                     // element tail (empty for Q=880880)
        int q = nquad * 4 + tid;
        if (q < Q) { TESTK(mus[q], sigmas[q]) }
    }
#undef TESTK

    // final flush
    __syncthreads();
    {
        const int n = cnt;
        for (int j = wid; j < n; j += 4) {
            float2 p = buf[j];
            float r = fmaf(p.x, p.x, p.y * p.y);
#pragma unroll
            for (int k = 0; k < 4; ++k)
                acc[k] = fminf(acc[k], fmaf(m2[k], p.x, fmaf(s2[k], p.y, r)));
        }
    }

    // merge 4 waves, un-shift by c_b = m_b^2 + s_b^2, write private partial
    __syncthreads();
#pragma unroll
    for (int k = 0; k < 4; ++k) red[wid][lane + 64 * k] = acc[k];
    __syncthreads();
    {
        float v = fminf(fminf(red[0][tid], red[1][tid]), fminf(red[2][tid], red[3][tid]));
        v = v + fmaf(mb, mb, sb * sb);
        partial[(size_t)b * NB + tid] = fmaxf(v, 0.f);
    }
}

// ---------------------------------------------------------------------------
// K3: one block per sample; min over NB partials (one per thread) + transform.
// ---------------------------------------------------------------------------
__global__ __launch_bounds__(256) void reduce_kernel(const float* __restrict__ partial,
                                                     float* __restrict__ out) {
    const int b   = blockIdx.x;
    const int tid = threadIdx.x;
    const int lane = tid & 63, wid = tid >> 6;
    float v = partial[(size_t)tid * NB + b];
#pragma unroll
    for (int off = 32; off > 0; off >>= 1)
        v = fminf(v, __shfl_down(v, off, 64));
    __shared__ float w[4];
    if (lane == 0) w[wid] = v;
    __syncthreads();
    if (tid == 0) {
        float m = fminf(fminf(w[0], w[1]), fminf(w[2], w[3]));
        out[b] = expf(-T_K * sqrtf(m));
    }
}

extern "C" void kernel_launch(void* const* d_in, const int* in_sizes, int n_in,
                              void* d_out, int out_size, void* d_ws, size_t ws_size,
                              hipStream_t stream) {
    const float* features = (const float*)d_in[0];
    // d_in[1]=labels, d_in[2]=pred, d_in[3]=confidence -- unused by reference
    const float* queue_mus    = (const float*)d_in[4];
    const float* queue_sigmas = (const float*)d_in[5];
    const int Q = in_sizes[4];

    float* stats   = (float*)d_ws;                 // 2*NB floats
    float* partial = stats + 2 * NB;               // NB*NB floats (256 KB)

    stats_kernel<<<NB, 256, 0, stream>>>(features, stats);
    scan_pruned_kernel<<<NB, 256, 0, stream>>>(queue_mus, queue_sigmas, stats,
                                               partial, Q);
    reduce_kernel<<<NB, 256, 0, stream>>>(partial, (float*)d_out);
}